// Round 11
// baseline (151.058 us; speedup 1.0000x reference)
//
#include <hip/hip_runtime.h>
#include <hip/hip_bf16.h>

// out[b,i] = sum_{j<=i} x[b,j] * kernel[i-j]   (causal Toeplitz matmul)
// M=2048, N=K=4096. f32 in/out, bf16 MFMA compute.
//
// R16: 64x64 wave tiles via 4-way K-split. Evidence R13-R15: binding
// constraints are A-L2 traffic (min 540MB needs 64-ROW waves; R15's col-split
// doubled it to 1.08GB -> L2 saturated at 22.5TB/s, +13us) and B-LDS-port
// bytes (prop 1/waverows; R13's 32-row waves -> 21us floor). Satisfy both:
// block = 64 rows x 128 cols, 512 thr = 4 K-groups (K=32/step) x 2 waves;
// wave = 64x64 C-tile (fm4, fn4, kk1). Port 2112 reads/CU = 10.5us (half
// R13), A 540MB (half R15), matrix 4.3us -- all pipes < 11us, overlapped in
// the barrier-free loop. R13's uniform 33-step ct-pair blocks, XCD panel
// affinity, whole-window B staging: verbatim. New: 4-way combine tree
// (g0+=g1 | g2+=g3, then g0+=g2) in the dead phase-1 window region (36864B
// overlay <= 38016B min region). acc 64 AGPR + ~60 VGPR <= 128 combined.

typedef unsigned short u16;
typedef __attribute__((ext_vector_type(8))) short  bf16x8;
typedef __attribute__((ext_vector_type(8))) unsigned short u16x8;
typedef __attribute__((ext_vector_type(4))) float  f32x4;

#define KDIM 4096
#define NDIM 4096
#define MDIM 2048
#define KREV_STRIDE 4608                    // elems per shifted copy (global)
#define KREV_BYTES  (8 * KREV_STRIDE * 2)   // 73728

#define MFMA_BF16 __builtin_amdgcn_mfma_f32_16x16x32_bf16

static __device__ inline u16 f2bf(float f) {
  unsigned u = __builtin_bit_cast(unsigned, f);
  unsigned r = u + 0x7FFFu + ((u >> 16) & 1u);
  return (u16)(r >> 16);
}

static __device__ inline void async_copy16(const void* g, void* l) {
  __builtin_amdgcn_global_load_lds((const __attribute__((address_space(1))) void*)g,
                                   (__attribute__((address_space(3))) void*)l,
                                   16, 0, 0);
}

// Fused prep: blocks [0, conv_blocks) convert x->bf16 into the fragment-tiled
// layout; last 18 blocks build 8 shifted krev copies.
// Tiled layout: elem index = (rg*128 + kb)*512 + l*8 + e, where the 8 elems e
// are x[row = rg*16 + (l&15)][k = kb*32 + (l>>4)*8 + e]. One wave's fragment
// load (fixed rg,kb; l=lane) is 1KB contiguous.
__global__ __launch_bounds__(256) void prep(const float* __restrict__ x,
                                            const float* __restrict__ kern,
                                            u16* __restrict__ xb,
                                            u16* __restrict__ krevs,
                                            int conv_blocks) {
  int kblk = (int)blockIdx.x - conv_blocks;
  if (kblk >= 0) {
    int u = kblk * 256 + threadIdx.x;
    for (int a = 0; a < 8; ++a) {
      int t = u + a - 8;
      u16 v = 0;
      if (t >= 0 && t <= 4095) v = f2bf(kern[4095 - t]);
      krevs[a * KREV_STRIDE + u] = v;
    }
  } else {
    unsigned tg  = blockIdx.x * 256 + threadIdx.x;   // 0..2048*4096/8-1
    unsigned l   = tg & 63;
    unsigned kb  = (tg >> 6) & 127;
    unsigned rg  = tg >> 13;                         // 0..127
    unsigned row = rg * 16 + (l & 15);
    unsigned k   = kb * 32 + (l >> 4) * 8;
    const f32x4* p = (const f32x4*)(x + (size_t)row * KDIM + k);
    f32x4 v0 = p[0], v1 = p[1];
    u16x8 r;
    r[0] = f2bf(v0[0]); r[1] = f2bf(v0[1]); r[2] = f2bf(v0[2]); r[3] = f2bf(v0[3]);
    r[4] = f2bf(v1[0]); r[5] = f2bf(v1[1]); r[6] = f2bf(v1[2]); r[7] = f2bf(v1[3]);
    *(u16x8*)(xb + (size_t)tg * 8) = r;              // coalesced 1KB/wave
  }
}

template <bool CONV>
__global__ __launch_bounds__(512, 4) void toeplitz_gemm(const void* __restrict__ Av,
                                                        const u16* __restrict__ krevs,
                                                        float* __restrict__ out) {
  // LDS: two B windows, 8 copies each, stride_q = 128(ctq+1)+200 elems
  // (==8 mod 64, a*16B bank phase); stride1+stride2 = 4624 -> 73984 B fixed.
  // Phase-1 region (8*stride1*2 >= 38016 B, dead after phase-1 compute)
  // hosts the 2x18432 B combine overlay; phase-2 region stays intact.
  __shared__ __align__(16) char smem_raw[73984];
  u16*   B_all = (u16*)smem_raw;
  f32x4* epA   = (f32x4*)smem_raw;              // combine overlay A (g1 / g2)
  f32x4* epB   = (f32x4*)(smem_raw + 18432);    // combine overlay B (g3)

  const int tid  = threadIdx.x;
  const int w    = tid >> 6;        // 0..7
  const int g    = w >> 1;          // K-group 0..3 (K=32 slices)
  const int wn   = w & 1;           // 64-col half
  const int lane = tid & 63;
  const int lane16 = lane & 15;
  const int quad   = lane >> 4;

  // XCD-affine uniform mapping (R13 verbatim): XCD x_=b&7 owns 128-row
  // panels {x_, x_+8}; every block = one 64-row tile x ct-pair {31-ctp, ctp}
  // run sequentially = 33 K-steps (uniform).
  const int b   = (int)blockIdx.x;
  const int x_  = b & 7;
  const int jj  = b >> 3;                 // 0..63 within XCD
  const int p_  = x_ + 8 * (jj & 1);      // 128-row panel 0..15
  const int mt2 = p_ * 2 + ((jj >> 1) & 1); // 64-row tile 0..31
  const int ctp = jj >> 2;                // 0..15
  const int ct1 = 31 - ctp;               // phase 1 (big, >=16)
  const int ct2 = ctp;                    // phase 2
  const int m0  = mt2 * 64;

  const int stride1 = 128 * (ct1 + 1) + 200;
  const int stride2 = 128 * (ct2 + 1) + 200;
  const int base2   = 8 * stride1;        // elems
  const int W1 = 3968 - 128 * ct1;
  const int W2 = 3968 - 128 * ct2;

  // A addressing: SGPR-ized group index; elem(fm,t) =
  // (mt2*4 + fm)*65536 + g*512 + t*2048 + lane*8.
  const int gu = __builtin_amdgcn_readfirstlane(g);
  const u16*   xb2 = (const u16*)Av;
  const float* xf  = (const float*)Av;
  int aoffs[4];
  for (int fm = 0; fm < 4; ++fm)
    aoffs[fm] = (mt2 * 4 + fm) * 65536 + gu * 512 + lane * 8;
  const int rowb = m0 + lane16;           // CONV source row base

  auto ldA = [&](int fm, int t) -> bf16x8 {
    return *(const bf16x8*)(xb2 + aoffs[fm] + t * 2048);
  };
  auto ldAc = [&](int fm, int t) -> bf16x8 {
    const float* px = xf + (size_t)(rowb + fm * 16) * KDIM +
                      t * 128 + gu * 32 + quad * 8;
    f32x4 v0 = *(const f32x4*)px, v1 = *(const f32x4*)(px + 4);
    u16x8 r;
    r[0]=f2bf(v0[0]); r[1]=f2bf(v0[1]); r[2]=f2bf(v0[2]); r[3]=f2bf(v0[3]);
    r[4]=f2bf(v1[0]); r[5]=f2bf(v1[1]); r[6]=f2bf(v1[2]); r[7]=f2bf(v1[3]);
    return __builtin_bit_cast(bf16x8, r);
  };

  // ---- prologue: stage BOTH B windows (wave w stages copy w of each) ----
  auto stageWin = [&](int base_e, int stride_e, int Wp) {
    const u16* src = krevs + w * KREV_STRIDE + Wp;
    char* dstb = smem_raw + (size_t)(base_e + w * stride_e) * 2;
    for (int c = 0; c * 512 < stride_e; ++c) {
      int idx = c * 512 + lane * 8;
      if (idx < stride_e)
        async_copy16(src + idx, dstb + (size_t)c * 1024);
    }
  };
  stageWin(0, stride1, W1);
  stageWin(base2, stride2, W2);
  asm volatile("s_waitcnt vmcnt(0)" ::: "memory");
  __builtin_amdgcn_s_barrier();
  asm volatile("" ::: "memory");

  // ---- one phase: barrier-free K loop + 4-way combine tree + epilogue ----
  auto runPhase = [&](int ctq, int base_e, int stride_q, int Wq) {
    const int n0q = ctq * 128;
    int boff[4];
    for (int fn = 0; fn < 4; ++fn) {
      int n_g = n0q + wn * 64 + fn * 16 + lane16;
      int s0  = 4095 - n_g + quad * 8;
      int a   = s0 & 7;
      boff[fn] = base_e + a * stride_q + (s0 - a + 8 - Wq);
    }
    f32x4 acc[4][4] = {};

    if constexpr (!CONV) {
      bf16x8 afA[4], afB[4];
#pragma unroll
      for (int fm = 0; fm < 4; ++fm) afA[fm] = ldA(fm, 0);
      for (int t = 0; ; ) {
        {  // even step: consume afA, prefetch afB(t+1)
          const int ks = t * 128 + g * 32;
          bf16x8 bv[4];
#pragma unroll
          for (int fn = 0; fn < 4; ++fn)
            bv[fn] = *(const bf16x8*)(&B_all[boff[fn] + ks]);
          if (t < ctq)
#pragma unroll
            for (int fm = 0; fm < 4; ++fm) afB[fm] = ldA(fm, t + 1);
#pragma unroll
          for (int fn = 0; fn < 4; ++fn)
#pragma unroll
            for (int fm = 0; fm < 4; ++fm)
              acc[fm][fn] = MFMA_BF16(afA[fm], bv[fn], acc[fm][fn], 0, 0, 0);
          if (t == ctq) break;
          ++t;
        }
        {  // odd step: consume afB, prefetch afA(t+1)
          const int ks = t * 128 + g * 32;
          bf16x8 bv[4];
#pragma unroll
          for (int fn = 0; fn < 4; ++fn)
            bv[fn] = *(const bf16x8*)(&B_all[boff[fn] + ks]);
          if (t < ctq)
#pragma unroll
            for (int fm = 0; fm < 4; ++fm) afA[fm] = ldA(fm, t + 1);
#pragma unroll
          for (int fn = 0; fn < 4; ++fn)
#pragma unroll
            for (int fm = 0; fm < 4; ++fm)
              acc[fm][fn] = MFMA_BF16(afB[fm], bv[fn], acc[fm][fn], 0, 0, 0);
          if (t == ctq) break;
          ++t;
        }
      }
    } else {
      for (int t = 0; t <= ctq; ++t) {
        const int ks = t * 128 + g * 32;
        bf16x8 af[4];
#pragma unroll
        for (int fm = 0; fm < 4; ++fm) af[fm] = ldAc(fm, t);
#pragma unroll
        for (int fn = 0; fn < 4; ++fn) {
          bf16x8 bv = *(const bf16x8*)(&B_all[boff[fn] + ks]);
#pragma unroll
          for (int fm = 0; fm < 4; ++fm)
            acc[fm][fn] = MFMA_BF16(af[fm], bv, acc[fm][fn], 0, 0, 0);
        }
      }
    }

    // combine tree: round 1 {g0+=g1 via epA, g2+=g3 via epB}, round 2
    // {g0+=g2 via epA}; each in 2 half-rounds (8 f32x4) to fit 36864 B.
    // Overlay lives in the phase-1 window region (dead after phase-1).
    const int j9 = (wn * 64 + lane) * 9;
    __syncthreads();                       // all groups done computing
#pragma unroll
    for (int hh = 0; hh < 2; ++hh) {
      if (g == 1)
        for (int f2 = 0; f2 < 2; ++f2)
          for (int fn = 0; fn < 4; ++fn)
            epA[j9 + f2 * 4 + fn] = acc[hh * 2 + f2][fn];
      if (g == 3)
        for (int f2 = 0; f2 < 2; ++f2)
          for (int fn = 0; fn < 4; ++fn)
            epB[j9 + f2 * 4 + fn] = acc[hh * 2 + f2][fn];
      __syncthreads();
      if (g == 0)
        for (int f2 = 0; f2 < 2; ++f2)
          for (int fn = 0; fn < 4; ++fn)
            acc[hh * 2 + f2][fn] += epA[j9 + f2 * 4 + fn];
      if (g == 2)
        for (int f2 = 0; f2 < 2; ++f2)
          for (int fn = 0; fn < 4; ++fn)
            acc[hh * 2 + f2][fn] += epB[j9 + f2 * 4 + fn];
      __syncthreads();
    }
#pragma unroll
    for (int hh = 0; hh < 2; ++hh) {
      if (g == 2)
        for (int f2 = 0; f2 < 2; ++f2)
          for (int fn = 0; fn < 4; ++fn)
            epA[j9 + f2 * 4 + fn] = acc[hh * 2 + f2][fn];
      __syncthreads();
      if (g == 0)
        for (int f2 = 0; f2 < 2; ++f2)
          for (int fn = 0; fn < 4; ++fn)
            acc[hh * 2 + f2][fn] += epA[j9 + f2 * 4 + fn];
      __syncthreads();
    }

    // epilogue (group 0 only): C/D layout col=lane&15, row=quad*4+r
    if (g == 0) {
      for (int fm = 0; fm < 4; ++fm) {
        int row_base = m0 + fm * 16 + quad * 4;
        for (int fn = 0; fn < 4; ++fn) {
          int col = n0q + wn * 64 + fn * 16 + lane16;
          for (int r = 0; r < 4; ++r)
            out[(size_t)(row_base + r) * NDIM + col] = acc[fm][fn][r];
        }
      }
    }
  };

  runPhase(ct1, 0, stride1, W1);       // big phase first (region >= 38016 B)
  runPhase(ct2, base2, stride2, W2);   // its window untouched by the overlay
}

extern "C" void kernel_launch(void* const* d_in, const int* in_sizes, int n_in,
                              void* d_out, int out_size, void* d_ws, size_t ws_size,
                              hipStream_t stream) {
  const float* x    = (const float*)d_in[0];
  const float* kern = (const float*)d_in[1];
  float* out = (float*)d_out;

  u16* krevs = (u16*)d_ws;
  u16* xb    = (u16*)((char*)d_ws + KREV_BYTES);
  const size_t need_fast = (size_t)KREV_BYTES + (size_t)MDIM * KDIM * 2;

  if (ws_size >= need_fast) {
    prep<<<4096 + 18, 256, 0, stream>>>(x, kern, xb, krevs, 4096);
    toeplitz_gemm<false><<<512, 512, 0, stream>>>(xb, krevs, out);
  } else {
    prep<<<18, 256, 0, stream>>>(x, kern, xb, krevs, 0);
    toeplitz_gemm<true><<<512, 512, 0, stream>>>(x, krevs, out);
  }
}

// Round 12
// 113.963 us; speedup vs baseline: 1.3255x; 1.3255x over previous
//
#include <hip/hip_runtime.h>
#include <hip/hip_bf16.h>

// out[b,i] = sum_{j<=i} x[b,j] * kernel[i-j]   (causal Toeplitz matmul)
// M=2048, N=K=4096. f32 in/out, bf16 MFMA compute.
//
// R17: fm=4 geometry at the 256-reg occupancy point. R16 proved the tile
// algebra (B-reads/MFMA=1/4 -> port 10.5us; 64-row waves -> A 540MB) but
// spilled: acc64+af32+bv16+addr ~132 regs > the 128 cap that 2 blocks/CU
// (launch_bounds 512,4) imposes -> FETCH +17MB / WRITE +43MB of scratch, 76us.
// Fix: 1 block/CU, __launch_bounds__(512,2) -> 256 regs/thread. 256 blocks of
// 128x128 (16 panels x 16 ct-pairs, uniform 33 steps, single dispatch round,
// zero tail). 8 waves = 2 K-groups(K=64) x 2wm x 2wn; wave = 64x64 (fm4 fn4
// kk2), acc 64 + af dbuf 32 + bv dbuf 32 + addr ~150 regs, NO spill, ~100
// regs headroom. TLP 2 waves/SIMD; latency covered by ILP: bv 1 kk ahead
// (~620cyc cover vs 120 LDS), af 1 t ahead (~1240 vs ~400 L2) - R14's proven
// ping-pong. XCD x owns panels {x,x+8} (2MB L2). Whole-window B staging,
// barrier-free K loop, R13 combine/epilogue verbatim.

typedef unsigned short u16;
typedef __attribute__((ext_vector_type(8))) short  bf16x8;
typedef __attribute__((ext_vector_type(8))) unsigned short u16x8;
typedef __attribute__((ext_vector_type(4))) float  f32x4;

#define KDIM 4096
#define NDIM 4096
#define MDIM 2048
#define KREV_STRIDE 4608                    // elems per shifted copy (global)
#define KREV_BYTES  (8 * KREV_STRIDE * 2)   // 73728

#define MFMA_BF16 __builtin_amdgcn_mfma_f32_16x16x32_bf16

static __device__ inline u16 f2bf(float f) {
  unsigned u = __builtin_bit_cast(unsigned, f);
  unsigned r = u + 0x7FFFu + ((u >> 16) & 1u);
  return (u16)(r >> 16);
}

static __device__ inline void async_copy16(const void* g, void* l) {
  __builtin_amdgcn_global_load_lds((const __attribute__((address_space(1))) void*)g,
                                   (__attribute__((address_space(3))) void*)l,
                                   16, 0, 0);
}

// Fused prep: blocks [0, conv_blocks) convert x->bf16 into the fragment-tiled
// layout; last 18 blocks build 8 shifted krev copies.
// Tiled layout: elem index = (rg*128 + kb)*512 + l*8 + e, where the 8 elems e
// are x[row = rg*16 + (l&15)][k = kb*32 + (l>>4)*8 + e]. One wave's fragment
// load (fixed rg,kb; l=lane) is 1KB contiguous.
__global__ __launch_bounds__(256) void prep(const float* __restrict__ x,
                                            const float* __restrict__ kern,
                                            u16* __restrict__ xb,
                                            u16* __restrict__ krevs,
                                            int conv_blocks) {
  int kblk = (int)blockIdx.x - conv_blocks;
  if (kblk >= 0) {
    int u = kblk * 256 + threadIdx.x;
    for (int a = 0; a < 8; ++a) {
      int t = u + a - 8;
      u16 v = 0;
      if (t >= 0 && t <= 4095) v = f2bf(kern[4095 - t]);
      krevs[a * KREV_STRIDE + u] = v;
    }
  } else {
    unsigned tg  = blockIdx.x * 256 + threadIdx.x;   // 0..2048*4096/8-1
    unsigned l   = tg & 63;
    unsigned kb  = (tg >> 6) & 127;
    unsigned rg  = tg >> 13;                         // 0..127
    unsigned row = rg * 16 + (l & 15);
    unsigned k   = kb * 32 + (l >> 4) * 8;
    const f32x4* p = (const f32x4*)(x + (size_t)row * KDIM + k);
    f32x4 v0 = p[0], v1 = p[1];
    u16x8 r;
    r[0] = f2bf(v0[0]); r[1] = f2bf(v0[1]); r[2] = f2bf(v0[2]); r[3] = f2bf(v0[3]);
    r[4] = f2bf(v1[0]); r[5] = f2bf(v1[1]); r[6] = f2bf(v1[2]); r[7] = f2bf(v1[3]);
    *(u16x8*)(xb + (size_t)tg * 8) = r;              // coalesced 1KB/wave
  }
}

template <bool CONV>
__global__ __launch_bounds__(512, 2) void toeplitz_gemm(const void* __restrict__ Av,
                                                        const u16* __restrict__ krevs,
                                                        float* __restrict__ out) {
  // LDS: two B windows, 8 copies each, stride_q = 128(ctq+1)+200 elems
  // (==8 mod 64, a*16B bank phase); stride1+stride2 = 4624 -> 73984 B fixed.
  // Phase-1 region (8*stride1*2 >= 38016 B, dead after phase-1 compute)
  // hosts the 36864 B combine overlay; phase-2 region stays intact.
  __shared__ __align__(16) char smem_raw[73984];
  u16*   B_all = (u16*)smem_raw;
  f32x4* ep    = (f32x4*)smem_raw;            // combine overlay, 9 f32x4/slot

  const int tid  = threadIdx.x;
  const int w    = tid >> 6;        // 0..7
  const int g    = w >> 2;          // K-group 0..1 (K=64 each)
  const int wl   = w & 3;           // wave-in-group
  const int lane = tid & 63;
  const int lane16 = lane & 15;
  const int quad   = lane >> 4;
  const int wm = wl >> 1;           // 64-row half
  const int wn = wl & 1;            // 64-col half

  // XCD-affine uniform mapping: 256 blocks = 16 panels x 16 ct-pairs; XCD
  // x_=b&7 owns panels {x_, x_+8} (2 MB bf16, L2-resident). Every block =
  // 128 rows x ct-pair {31-ctp, ctp} run sequentially = 33 K-steps.
  const int b   = (int)blockIdx.x;
  const int x_  = b & 7;
  const int jj  = b >> 3;                 // 0..31 within XCD
  const int p_  = x_ + 8 * (jj & 1);      // 128-row panel 0..15
  const int ctp = jj >> 1;                // 0..15
  const int ct1 = 31 - ctp;               // phase 1 (big, >=16)
  const int ct2 = ctp;                    // phase 2
  const int m0  = p_ * 128;

  const int stride1 = 128 * (ct1 + 1) + 200;
  const int stride2 = 128 * (ct2 + 1) + 200;
  const int base2   = 8 * stride1;        // elems
  const int W1 = 3968 - 128 * ct1;
  const int W2 = 3968 - 128 * ct2;

  // A addressing (R11): SGPR-ized wave-uniform parts; elem(fm,t,kk) =
  // (p_*8 + wm*4 + fm)*65536 + g*1024 + t*2048 + kk*512 + lane*8.
  const int wmu = __builtin_amdgcn_readfirstlane(wm);
  const int gu  = __builtin_amdgcn_readfirstlane(g);
  const u16*   xb2 = (const u16*)Av;
  const float* xf  = (const float*)Av;
  int aoffs[4];
  for (int fm = 0; fm < 4; ++fm)
    aoffs[fm] = (p_ * 8 + wmu * 4 + fm) * 65536 + gu * 1024 + lane * 8;
  const int rowb = m0 + wm * 64 + lane16;   // CONV source row base

  auto ldA = [&](int fm, int t, int kk) -> bf16x8 {
    return *(const bf16x8*)(xb2 + aoffs[fm] + t * 2048 + kk * 512);
  };
  auto ldAc = [&](int fm, int t, int kk) -> bf16x8 {
    const float* px = xf + (size_t)(rowb + fm * 16) * KDIM +
                      t * 128 + gu * 64 + kk * 32 + quad * 8;
    f32x4 v0 = *(const f32x4*)px, v1 = *(const f32x4*)(px + 4);
    u16x8 r;
    r[0]=f2bf(v0[0]); r[1]=f2bf(v0[1]); r[2]=f2bf(v0[2]); r[3]=f2bf(v0[3]);
    r[4]=f2bf(v1[0]); r[5]=f2bf(v1[1]); r[6]=f2bf(v1[2]); r[7]=f2bf(v1[3]);
    return __builtin_bit_cast(bf16x8, r);
  };

  // ---- prologue: stage BOTH B windows (wave w stages copy w of each) ----
  auto stageWin = [&](int base_e, int stride_e, int Wp) {
    const u16* src = krevs + w * KREV_STRIDE + Wp;
    char* dstb = smem_raw + (size_t)(base_e + w * stride_e) * 2;
    for (int c = 0; c * 512 < stride_e; ++c) {
      int idx = c * 512 + lane * 8;
      if (idx < stride_e)
        async_copy16(src + idx, dstb + (size_t)c * 1024);
    }
  };
  stageWin(0, stride1, W1);
  stageWin(base2, stride2, W2);
  asm volatile("s_waitcnt vmcnt(0)" ::: "memory");
  __builtin_amdgcn_s_barrier();
  asm volatile("" ::: "memory");

  // ---- one phase: barrier-free K loop, af/bv ping-pong prefetch ----
  auto runPhase = [&](int ctq, int base_e, int stride_q, int Wq) {
    const int n0q = ctq * 128;
    int boff[4];
    for (int fn = 0; fn < 4; ++fn) {
      int n_g = n0q + wn * 64 + fn * 16 + lane16;
      int s0  = 4095 - n_g + quad * 8;
      int a   = s0 & 7;
      boff[fn] = base_e + a * stride_q + (s0 - a + 8 - Wq);
    }
    f32x4 acc[4][4] = {};

    if constexpr (!CONV) {
      bf16x8 afA[4], afB[4], bvA[4], bvB[4];
#pragma unroll
      for (int fm = 0; fm < 4; ++fm) afA[fm] = ldA(fm, 0, 0);
#pragma unroll
      for (int fm = 0; fm < 4; ++fm) afB[fm] = ldA(fm, 0, 1);
#pragma unroll
      for (int fn = 0; fn < 4; ++fn)
        bvA[fn] = *(const bf16x8*)(&B_all[boff[fn] + g * 64]);   // t=0, kk=0
      for (int t = 0; ; ++t) {
        const int ks = t * 128 + g * 64;
        // kk=0: prefetch bvB (kk=1), consume afA/bvA
#pragma unroll
        for (int fn = 0; fn < 4; ++fn)
          bvB[fn] = *(const bf16x8*)(&B_all[boff[fn] + ks + 32]);
#pragma unroll
        for (int fn = 0; fn < 4; ++fn)
#pragma unroll
          for (int fm = 0; fm < 4; ++fm)
            acc[fm][fn] = MFMA_BF16(afA[fm], bvA[fn], acc[fm][fn], 0, 0, 0);
        if (t < ctq)
#pragma unroll
          for (int fm = 0; fm < 4; ++fm) afA[fm] = ldA(fm, t + 1, 0);
        // kk=1: prefetch bvA (t+1, kk=0), consume afB/bvB
        if (t < ctq)
#pragma unroll
          for (int fn = 0; fn < 4; ++fn)
            bvA[fn] = *(const bf16x8*)(&B_all[boff[fn] + ks + 128]);
#pragma unroll
        for (int fn = 0; fn < 4; ++fn)
#pragma unroll
          for (int fm = 0; fm < 4; ++fm)
            acc[fm][fn] = MFMA_BF16(afB[fm], bvB[fn], acc[fm][fn], 0, 0, 0);
        if (t == ctq) break;
#pragma unroll
        for (int fm = 0; fm < 4; ++fm) afB[fm] = ldA(fm, t + 1, 1);
      }
    } else {
      for (int t = 0; t <= ctq; ++t) {
        const int ks = t * 128 + g * 64;
#pragma unroll
        for (int kk = 0; kk < 2; ++kk) {
          bf16x8 af[4];
#pragma unroll
          for (int fm = 0; fm < 4; ++fm) af[fm] = ldAc(fm, t, kk);
#pragma unroll
          for (int fn = 0; fn < 4; ++fn) {
            bf16x8 bv = *(const bf16x8*)(&B_all[boff[fn] + ks + kk * 32]);
#pragma unroll
            for (int fm = 0; fm < 4; ++fm)
              acc[fm][fn] = MFMA_BF16(af[fm], bv, acc[fm][fn], 0, 0, 0);
          }
        }
      }
    }

    // combine (R13 verbatim): group1 -> group0 via LDS overlay in the
    // phase-1 B region (dead after phase-1 compute); fused add + store.
    const int j = tid & 255;
#pragma unroll
    for (int r = 0; r < 2; ++r) {
      __syncthreads();
      if (g == 1) {
        for (int fm2 = 0; fm2 < 2; ++fm2)
          for (int fn = 0; fn < 4; ++fn)
            ep[j * 9 + fm2 * 4 + fn] = acc[r * 2 + fm2][fn];
      }
      __syncthreads();
      if (g == 0) {
        for (int fm2 = 0; fm2 < 2; ++fm2)
          for (int fn = 0; fn < 4; ++fn) {
            f32x4 v = acc[r * 2 + fm2][fn];
            f32x4 o = ep[j * 9 + fm2 * 4 + fn];
            v[0] += o[0]; v[1] += o[1]; v[2] += o[2]; v[3] += o[3];
            int fm = r * 2 + fm2;
            int row_base = m0 + wm * 64 + fm * 16 + quad * 4;
            int col = n0q + wn * 64 + fn * 16 + lane16;
            for (int rr = 0; rr < 4; ++rr)
              out[(size_t)(row_base + rr) * NDIM + col] = v[rr];
          }
      }
    }
  };

  runPhase(ct1, 0, stride1, W1);       // big phase first (region >= 38016 B)
  runPhase(ct2, base2, stride2, W2);   // its window untouched by the overlay
}

extern "C" void kernel_launch(void* const* d_in, const int* in_sizes, int n_in,
                              void* d_out, int out_size, void* d_ws, size_t ws_size,
                              hipStream_t stream) {
  const float* x    = (const float*)d_in[0];
  const float* kern = (const float*)d_in[1];
  float* out = (float*)d_out;

  u16* krevs = (u16*)d_ws;
  u16* xb    = (u16*)((char*)d_ws + KREV_BYTES);
  const size_t need_fast = (size_t)KREV_BYTES + (size_t)MDIM * KDIM * 2;

  if (ws_size >= need_fast) {
    prep<<<4096 + 18, 256, 0, stream>>>(x, kern, xb, krevs, 4096);
    toeplitz_gemm<false><<<256, 512, 0, stream>>>(xb, krevs, out);
  } else {
    prep<<<18, 256, 0, stream>>>(x, kern, xb, krevs, 0);
    toeplitz_gemm<true><<<256, 512, 0, stream>>>(x, krevs, out);
  }
}